// Round 17
// baseline (188.782 us; speedup 1.0000x reference)
//
#include <hip/hip_runtime.h>

#define B_      2
#define DIM_    256
#define N_      4096
#define HEADS_  8
#define DINNER_ 512

typedef _Float16 half_t;
typedef _Float16 half8  __attribute__((ext_vector_type(8)));
typedef _Float16 half4v __attribute__((ext_vector_type(4)));
typedef _Float16 half2v __attribute__((ext_vector_type(2)));
typedef float    floatx4 __attribute__((ext_vector_type(4)));

#define SCL_    1.4426950408889634f  // log2(e), baked into Q,K
#define SHIFT2_ 20.0f                // fixed softmax shift (log2 domain)

// K=32 granule (64kappa x 64mu): halfoff(kappa,mu) =
//   ((kappa>>5)*4 + (mu>>4))*512 + (((kappa>>3)&3)*16 + (mu&15))*8 + (kappa&7)
// V tiles use a K=32 granule with the PV slot map chosen so the P B-frag is
// lane-local (co-designed with the QK output layout).
// perm: [b][slab 0..23][ntile 0..63][4096 halfs]; slab<8: Q, <16: K, else V.
//   Q slabs store -2*SCL*q; K slabs store SCL*k.
// xTg:  [b][ntile 0..63][kslab 0..3][4096 halfs]  (fmap in granule layout)
// Distance augmentation: S~ = (-2SCLq)·(SCLk) + q2*1 + 1*k2 = SCL^2*d2 via one
// extra K=32 MFMA whose operands carry [q2_hi,q2_lo,1,1] / [1,1,k2_hi,k2_lo].

// ---------------- prep: weights -> A-frag fp16; fmap -> xTg granule fp16 -----
__global__ __launch_bounds__(256) void prep_all(const float* __restrict__ fmap,
                                                const float* __restrict__ w_qkv,
                                                const float* __restrict__ w_out,
                                                half_t* __restrict__ wqF,
                                                half_t* __restrict__ woF,
                                                half_t* __restrict__ xTg) {
    const int t = threadIdx.x, bx = blockIdx.x;
    __shared__ float Tl[64 * 68];
    if (bx < 96) {                 // w_qkv: 96 m-tiles x 256 k
        half_t* dst = wqF + (size_t)bx * 4096;
#pragma unroll
        for (int j = 0; j < 2; ++j) {
            const int cch = j * 256 + t;
            const int o = cch >> 4, m15 = cch & 15;
            const float4 a  = *(const float4*)&w_qkv[(size_t)(bx * 16 + m15) * 256 + o * 8];
            const float4 bb = *(const float4*)&w_qkv[(size_t)(bx * 16 + m15) * 256 + o * 8 + 4];
            half8 hv;
            hv[0] = (half_t)a.x;  hv[1] = (half_t)a.y;  hv[2] = (half_t)a.z;  hv[3] = (half_t)a.w;
            hv[4] = (half_t)bb.x; hv[5] = (half_t)bb.y; hv[6] = (half_t)bb.z; hv[7] = (half_t)bb.w;
            *(half8*)(dst + o * 128 + m15 * 8) = hv;
        }
    } else if (bx < 112) {         // w_out: 16 m-tiles x 512 k
        const int mt = bx - 96;
        half_t* dst = woF + (size_t)mt * 8192;
#pragma unroll
        for (int j = 0; j < 4; ++j) {
            const int cch = j * 256 + t;
            const int o = cch >> 4, m15 = cch & 15;
            const float4 a  = *(const float4*)&w_out[(size_t)(mt * 16 + m15) * 512 + o * 8];
            const float4 bb = *(const float4*)&w_out[(size_t)(mt * 16 + m15) * 512 + o * 8 + 4];
            half8 hv;
            hv[0] = (half_t)a.x;  hv[1] = (half_t)a.y;  hv[2] = (half_t)a.z;  hv[3] = (half_t)a.w;
            hv[4] = (half_t)bb.x; hv[5] = (half_t)bb.y; hv[6] = (half_t)bb.z; hv[7] = (half_t)bb.w;
            *(half8*)(dst + o * 128 + m15 * 8) = hv;
        }
    } else {                       // fmap [k][n] fp32 -> xTg granule fp16
        const int idx = bx - 112;
        const int n0 = (idx & 63) * 64, k0 = ((idx >> 6) & 3) * 64, b = idx >> 8;
        {
            const int kk = t >> 2, nq = (t & 3) * 16;
#pragma unroll
            for (int q = 0; q < 4; ++q) {
                float4 v = *(const float4*)&fmap[((size_t)b * DIM_ + k0 + kk) * N_ + n0 + nq + 4 * q];
                *(float4*)&Tl[kk * 68 + nq + 4 * q] = v;
            }
        }
        __syncthreads();
        {
            const int n = t >> 2, ko = (t & 3) * 16;   // kappa_local = ko..ko+15
            half8 h0, h1;
#pragma unroll
            for (int j = 0; j < 8; ++j) h0[j] = (half_t)Tl[(ko + j) * 68 + n];
#pragma unroll
            for (int j = 0; j < 8; ++j) h1[j] = (half_t)Tl[(ko + 8 + j) * 68 + n];
            half_t* dst = xTg + (((size_t)b * 64 + (n0 >> 6)) * 4 + (k0 >> 6)) * 4096;
            const int o0 = ((ko >> 5) * 4 + (n >> 4)) * 512 + (((ko >> 3) & 3) * 16 + (n & 15)) * 8;
            const int k8 = ko + 8;
            const int o1 = ((k8 >> 5) * 4 + (n >> 4)) * 512 + (((k8 >> 3) & 3) * 16 + (n & 15)) * 8;
            *(half8*)(dst + o0) = h0;
            *(half8*)(dst + o1) = h1;
        }
    }
}

// ---------------- GEMM1: qkv projection + fused sq; B staged in LDS ---------
// v4: by-pairing — each block computes TWO adjacent m-slabs (by = 2*by2, +1)
// per staged B-tile, halving xTg re-reads (grid y 24 -> 12). Same math and
// summation order per output element.
__global__ __launch_bounds__(256) void mm_qkv_mf(const half_t* __restrict__ wqF,
                                                 const half_t* __restrict__ xTg,
                                                 half_t* __restrict__ perm,
                                                 float* __restrict__ sq) {
    const int nt64 = blockIdx.x, by2 = blockIdx.y, b = blockIdx.z;
    const int t = threadIdx.x, w = t >> 6, L = t & 63, c = L & 15, g = L >> 4;

    const half_t* Ab0 = wqF + (size_t)(8 * by2 + w) * 4096;
    const half_t* Ab1 = Ab0 + 4 * 4096;
    const half_t* Bb  = xTg + (((size_t)b * 64 + nt64) * 4) * 4096;

    __shared__ __align__(16) char smraw[16384];
    half_t* Bsh = (half_t*)smraw;                 // 8192 halfs staged per phase
    half_t* VtH = (half_t*)smraw;                 // epilogue granule bounce (alias)
    float*  red = (float*)(smraw + 8192);         // sq reduction, stride 17

    const floatx4 fz = {0.f, 0.f, 0.f, 0.f};
    floatx4 acc0[4], acc1[4];
#pragma unroll
    for (int ns = 0; ns < 4; ++ns) { acc0[ns] = fz; acc1[ns] = fz; }

#pragma unroll
    for (int ph = 0; ph < 2; ++ph) {
        if (ph) __syncthreads();                   // waves done reading stage 0
#pragma unroll
        for (int j = 0; j < 4; ++j)
            *(half8*)&Bsh[(j * 256 + t) * 8] = *(const half8*)(Bb + ph * 8192 + (j * 256 + t) * 8);
        __syncthreads();
#pragma unroll
        for (int kk = 0; kk < 4; ++kk) {
            const int kc = ph * 4 + kk;
            const half8 af0 = *(const half8*)(Ab0 + (kc * 4 + g) * 128 + c * 8);
            const half8 af1 = *(const half8*)(Ab1 + (kc * 4 + g) * 128 + c * 8);
            const half_t* Bs = Bsh + (kk >> 1) * 4096 + (kk & 1) * 2048;
#pragma unroll
            for (int ns = 0; ns < 4; ++ns) {
                const half8 bf = *(const half8*)(Bs + ns * 512 + L * 8);
                acc0[ns] = __builtin_amdgcn_mfma_f32_16x16x32_f16(af0, bf, acc0[ns], 0, 0, 0);
                acc1[ns] = __builtin_amdgcn_mfma_f32_16x16x32_f16(af1, bf, acc1[ns], 0, 0, 0);
            }
        }
    }
    __syncthreads();                               // Bsh dead; VtH/red may write

#pragma unroll
    for (int e = 0; e < 2; ++e) {
        if (e) __syncthreads();                    // VtH/red reuse between halves
        const int by = by2 * 2 + e;
        half_t* dst = perm + (((size_t)(b * 24 + by) * 64 + nt64) << 12);
        if (by < 16) {
            // Q/K: f = SCL*val rounded to fp16; granule stores qs*f (qs=-2 for Q).
            const float qs = (by < 8) ? -2.0f : 1.0f;
            float part[4];
#pragma unroll
            for (int ns = 0; ns < 4; ++ns) {
                const floatx4 av4 = e ? acc1[ns] : acc0[ns];
                half_t m[4];
                float s = 0.f;
#pragma unroll
                for (int i = 0; i < 4; ++i) {
                    const half_t hq = (half_t)(av4[i] * SCL_);
                    const float f = (float)hq;
                    s = fmaf(f, f, s);
                    m[i] = (half_t)(qs * f);
                }
                part[ns] = s;
                const int off = ((w >> 1) * 4 + ns) * 512 + (((2 * w + (g >> 1)) & 3) * 16 + c) * 8 + 4 * (g & 1);
                half2v p0v, p1v;
                p0v[0] = m[0]; p0v[1] = m[1];
                p1v[0] = m[2]; p1v[1] = m[3];
                *(half2v*)(VtH + off)     = p0v;
                *(half2v*)(VtH + off + 2) = p1v;
            }
#pragma unroll
            for (int ns = 0; ns < 4; ++ns)
                red[(ns * 16 + (w * 4 + g)) * 17 + c] = part[ns];
            __syncthreads();
#pragma unroll
            for (int j = 0; j < 2; ++j)
                *(half8*)(dst + t * 16 + j * 8) = *(half8*)(VtH + t * 16 + j * 8);
            if (t < 64) {
                const int ns = t >> 4, cc = t & 15;
                float s = 0.f;
#pragma unroll
                for (int wg = 0; wg < 16; ++wg) s += red[(ns * 16 + wg) * 17 + cc];
                const int tens = by >> 3, hh = by & 7;
                sq[((size_t)(tens * 16 + b * 8 + hh)) * N_ + nt64 * 64 + ns * 16 + cc] = s;
            }
        } else {
            // V: j = 16ns+c (spatial key), dd = 16w+4g+i -> K=32 PV granule
#pragma unroll
            for (int ns = 0; ns < 4; ++ns) {
                const floatx4 av4 = e ? acc1[ns] : acc0[ns];
#pragma unroll
                for (int i = 0; i < 4; ++i)
                    VtH[((ns >> 1) * 4 + w) * 512 + ((c >> 2) * 16 + 4 * g + i) * 8 + (ns & 1) * 4 + (c & 3)] =
                        (half_t)av4[i];
            }
            __syncthreads();
#pragma unroll
            for (int j = 0; j < 2; ++j)
                *(half8*)(dst + t * 16 + j * 8) = *(half8*)(VtH + t * 16 + j * 8);
        }
    }
}

// ---------------- fused distance-attention, split-K x4, no-drain pipeline ----
// v7 = v5 math/structure + 2-live-S reorder + sched_group_barrier 1:3
// MFMA:VALU interleave. Mechanism: waves issue IN ORDER; a trans burst stalls
// the wave on the 16-cyc trans pipe, blocking later MFMAs. Pinning a
// fine-grained MFMA/trans interleave in emission order lets one wave keep
// both pipes fed (trans 1024 cyc/it hides all 44 MFMAs).
__global__ __launch_bounds__(512) void attn_mfma(const half_t* __restrict__ perm,
                                                 const float* __restrict__ sq,
                                                 half_t* __restrict__ oh,
                                                 float* __restrict__ lbuf) {
    const int bx = blockIdx.x;
    const int qb = bx & 15, kh = bx >> 4;
    const int h = blockIdx.y, b = blockIdx.z;
    const int bh = b * HEADS_ + h;

    const half_t* Qb = perm + ((size_t)(b * 24 + h) << 18);
    const half_t* Kb = perm + ((size_t)(b * 24 + 8 + h) << 18);
    const half_t* Vb = perm + ((size_t)(b * 24 + 16 + h) << 18);
    const float* q2a = sq + (size_t)bh * N_;
    const float* k2a = sq + (size_t)(16 + bh) * N_;

    __shared__ __align__(16) half_t Kl[2][4096];
    __shared__ __align__(16) half_t Vl[2][4096];
    __shared__ __align__(16) unsigned int k2lp[1024];   // packed {k2hi,k2lo}

    const int t = threadIdx.x, w = t >> 6, L = t & 63, c = L & 15, g = L >> 4;
    const floatx4 fz = {0.f, 0.f, 0.f, 0.f};

    // stage packed hi/lo k2 (4 KB) once; visible after iter-0 barrier
    {
        const float2 kv = *(const float2*)&k2a[kh * 1024 + t * 2];
        const half_t h0 = (half_t)kv.x; const half_t l0 = (half_t)(kv.x - (float)h0);
        const half_t h1 = (half_t)kv.y; const half_t l1 = (half_t)(kv.y - (float)h1);
        k2lp[t * 2]     = (unsigned)__builtin_bit_cast(unsigned short, h0) |
                          ((unsigned)__builtin_bit_cast(unsigned short, l0) << 16);
        k2lp[t * 2 + 1] = (unsigned)__builtin_bit_cast(unsigned short, h1) |
                          ((unsigned)__builtin_bit_cast(unsigned short, l1) << 16);
    }

    // persistent Q B-frags for 2 subtiles
    const int tl = w >> 1;
    const int p0 = (w & 1) * 2, p1 = p0 + 1;
    const half_t* Qt = Qb + ((size_t)(qb * 4 + tl) << 12);
    const half8 bq0a = *(const half8*)(Qt + (0 * 4 + p0) * 512 + L * 8);
    const half8 bq1a = *(const half8*)(Qt + (1 * 4 + p0) * 512 + L * 8);
    const half8 bq0b = *(const half8*)(Qt + (0 * 4 + p1) * 512 + L * 8);
    const half8 bq1b = *(const half8*)(Qt + (1 * 4 + p1) * 512 + L * 8);

    union U8 { half8 v; unsigned int u[4]; };
    // aug B-frags: lanes L<16 (kappa'0..7) = {q2hi,q2lo,1,1,0..}; others zero
    U8 qXa, qXb;
    {
        const float q2la = q2a[qb * 256 + 64 * tl + 16 * p0 + c];
        const float q2lb = q2a[qb * 256 + 64 * tl + 16 * p1 + c];
        const half_t ha = (half_t)q2la; const half_t la = (half_t)(q2la - (float)ha);
        const half_t hb = (half_t)q2lb; const half_t lb_ = (half_t)(q2lb - (float)hb);
        const unsigned pka = (unsigned)__builtin_bit_cast(unsigned short, ha) |
                             ((unsigned)__builtin_bit_cast(unsigned short, la) << 16);
        const unsigned pkb = (unsigned)__builtin_bit_cast(unsigned short, hb) |
                             ((unsigned)__builtin_bit_cast(unsigned short, lb_) << 16);
        const bool lo16 = (L < 16);
        qXa.u[0] = lo16 ? pka : 0u; qXa.u[1] = lo16 ? 0x3C003C00u : 0u;
        qXa.u[2] = 0u; qXa.u[3] = 0u;
        qXb.u[0] = lo16 ? pkb : 0u; qXb.u[1] = lo16 ? 0x3C003C00u : 0u;
        qXb.u[2] = 0u; qXb.u[3] = 0u;
    }

    half8 aone8;   // ones row m=0 for K=32 l-MFMA
    {
        const half_t ov = (c == 0) ? (half_t)1.0f : (half_t)0.0f;
        aone8[0] = ov; aone8[1] = ov; aone8[2] = ov; aone8[3] = ov;
        aone8[4] = ov; aone8[5] = ov; aone8[6] = ov; aone8[7] = ov;
    }

    floatx4 Oa[4], Ob[4];
    floatx4 laca = fz, lacb = fz;
#pragma unroll
    for (int dt = 0; dt < 4; ++dt) { Oa[dt] = fz; Ob[dt] = fz; }

    const int kt0 = kh * 16;
    half8 rk = *(const half8*)(Kb + ((size_t)kt0 << 12) + t * 8);
    half8 rv = *(const half8*)(Vb + ((size_t)kt0 << 12) + t * 8);

    union H8 { half8 v; half2v h2[4]; };

#define QKC(J, SA, SB) { \
    const half8 ak0 = *(const half8*)(&Kl[buf][(0 * 4 + (J)) * 512 + L * 8]); \
    const half8 ak1 = *(const half8*)(&Kl[buf][(1 * 4 + (J)) * 512 + L * 8]); \
    U8 kX; kX.u[0] = 0x3C003C00u; kX.u[1] = k2lp[it * 64 + (J) * 16 + c]; \
    kX.u[2] = 0u; kX.u[3] = 0u; \
    SA = __builtin_amdgcn_mfma_f32_16x16x32_f16(ak0, bq0a, fz, 0, 0, 0); \
    SA = __builtin_amdgcn_mfma_f32_16x16x32_f16(ak1, bq1a, SA, 0, 0, 0); \
    SA = __builtin_amdgcn_mfma_f32_16x16x32_f16(kX.v, qXa.v, SA, 0, 0, 0); \
    SB = __builtin_amdgcn_mfma_f32_16x16x32_f16(ak0, bq0b, fz, 0, 0, 0); \
    SB = __builtin_amdgcn_mfma_f32_16x16x32_f16(ak1, bq1b, SB, 0, 0, 0); \
    SB = __builtin_amdgcn_mfma_f32_16x16x32_f16(kX.v, qXb.v, SB, 0, 0, 0); }

#define SMX(SA, SB, SLOT, UA, UB) { \
    float pa[4], pb[4]; \
    _Pragma("unroll") \
    for (int i = 0; i < 4; ++i) { \
        pa[i] = __builtin_amdgcn_exp2f(__builtin_amdgcn_sqrtf(__builtin_fabsf(SA[i])) - SHIFT2_); \
        pb[i] = __builtin_amdgcn_exp2f(__builtin_amdgcn_sqrtf(__builtin_fabsf(SB[i])) - SHIFT2_); } \
    UA.h2[2 * (SLOT)]     = __builtin_bit_cast(half2v, __builtin_amdgcn_cvt_pkrtz(pa[0], pa[1])); \
    UA.h2[2 * (SLOT) + 1] = __builtin_bit_cast(half2v, __builtin_amdgcn_cvt_pkrtz(pa[2], pa[3])); \
    UB.h2[2 * (SLOT)]     = __builtin_bit_cast(half2v, __builtin_amdgcn_cvt_pkrtz(pb[0], pb[1])); \
    UB.h2[2 * (SLOT) + 1] = __builtin_bit_cast(half2v, __builtin_amdgcn_cvt_pkrtz(pb[2], pb[3])); }

#define LPV(NTP, UA, UB) { \
    laca = __builtin_amdgcn_mfma_f32_16x16x32_f16(aone8, UA.v, laca, 0, 0, 0); \
    lacb = __builtin_amdgcn_mfma_f32_16x16x32_f16(aone8, UB.v, lacb, 0, 0, 0); \
    _Pragma("unroll") \
    for (int dt = 0; dt < 4; ++dt) { \
        const half8 av = *(const half8*)(&Vl[buf][((NTP) * 4 + dt) * 512 + L * 8]); \
        Oa[dt] = __builtin_amdgcn_mfma_f32_16x16x32_f16(av, UA.v, Oa[dt], 0, 0, 0); \
        Ob[dt] = __builtin_amdgcn_mfma_f32_16x16x32_f16(av, UB.v, Ob[dt], 0, 0, 0); } }

    for (int it = 0; it < 16; ++it) {
        const int buf = it & 1;
        *(half8*)(&Kl[buf][t * 8]) = rk;     // waits vmcnt for rk/rv data dep only
        *(half8*)(&Vl[buf][t * 8]) = rv;
        // LDS-only barrier: vmcnt (prefetch) stays outstanding across it.
        asm volatile("s_waitcnt lgkmcnt(0)\n\ts_barrier" ::: "memory");
        if (it < 15) {                        // prefetch overlaps compute below
            rk = *(const half8*)(Kb + ((size_t)(kt0 + it + 1) << 12) + t * 8);
            rv = *(const half8*)(Vb + ((size_t)(kt0 + it + 1) << 12) + t * 8);
        }

        // 2-live-S order (max 2 S-tiles live; same accumulation order as v5)
        floatx4 S0a, S0b, S1a, S1b, S2a, S2b, S3a, S3b;
        H8 u0a, u0b, u1a, u1b;
        QKC(0, S0a, S0b)
        QKC(1, S1a, S1b)
        SMX(S0a, S0b, 0, u0a, u0b)
        QKC(2, S2a, S2b)
        SMX(S1a, S1b, 1, u0a, u0b)
        QKC(3, S3a, S3b)
        LPV(0, u0a, u0b)
        SMX(S2a, S2b, 0, u1a, u1b)
        SMX(S3a, S3b, 1, u1a, u1b)
        LPV(1, u1a, u1b)

        // pin fine-grained MFMA:VALU interleave (44 MFMA, ~132 VALU, 20 ds_read)
#pragma unroll
        for (int sg = 0; sg < 44; ++sg) {
            __builtin_amdgcn_sched_group_barrier(0x008, 1, 0);   // 1 MFMA
            __builtin_amdgcn_sched_group_barrier(0x002, 3, 0);   // 3 VALU
            if ((sg & 3) == 1)
                __builtin_amdgcn_sched_group_barrier(0x100, 2, 0); // 2 DS_READ
        }
    }
#undef QKC
#undef SMX
#undef LPV

    // write unnormalized O-quarters (fp16, K=32 granule: kappa=dd, mu=16*plane+c)
    const int ntile = qb * 4 + tl;
    half_t* dst = oh + (size_t)kh * 4194304 + (((size_t)bh * 64 + ntile) << 12);
#pragma unroll
    for (int dt = 0; dt < 4; ++dt) {
        const int obase = ((dt >> 1) * 4) * 512 + (((2 * dt + (g >> 1)) & 3) * 16 + c) * 8 + 4 * (g & 1);
        const half2v a0 = __builtin_bit_cast(half2v, __builtin_amdgcn_cvt_pkrtz(Oa[dt][0], Oa[dt][1]));
        const half2v a1 = __builtin_bit_cast(half2v, __builtin_amdgcn_cvt_pkrtz(Oa[dt][2], Oa[dt][3]));
        *(half2v*)(dst + obase + p0 * 512)     = a0;
        *(half2v*)(dst + obase + p0 * 512 + 2) = a1;
        const half2v b0 = __builtin_bit_cast(half2v, __builtin_amdgcn_cvt_pkrtz(Ob[dt][0], Ob[dt][1]));
        const half2v b1 = __builtin_bit_cast(half2v, __builtin_amdgcn_cvt_pkrtz(Ob[dt][2], Ob[dt][3]));
        *(half2v*)(dst + obase + p1 * 512)     = b0;
        *(half2v*)(dst + obase + p1 * 512 + 2) = b1;
    }
    // l: row m=0 of lac -> lanes 0..15, reg 0
    if (L < 16) {
        const size_t lb0 = (size_t)kh * 65536 + (size_t)bh * N_ + qb * 256 + 64 * tl;
        lbuf[lb0 + 16 * p0 + L] = laca[0];
        lbuf[lb0 + 16 * p1 + L] = lacb[0];
    }
}

// ---------------- GEMM3: out projection + split-K x4 combine inline ----------
// v3: column-split — each block handles a 32-col half-tile (grid 128x4x2).
__global__ __launch_bounds__(256) void mm_out_mf(const half_t* __restrict__ woF,
                                                 const half_t* __restrict__ oh,
                                                 const float* __restrict__ lbuf,
                                                 float* __restrict__ out) {
    const int bx = blockIdx.x;               // nt = bx>>1 (64-col tile), hf = bx&1
    const int nt = bx >> 1, hf = bx & 1;
    const int mb = blockIdx.y, b = blockIdx.z;
    const int t = threadIdx.x, w = t >> 6, L = t & 63, c = L & 15, g = L >> 4;
    const int mt = mb * 4 + w;

    const half_t* Ab = woF + (size_t)mt * 8192;
    const floatx4 fz = {0.f, 0.f, 0.f, 0.f};
    floatx4 O4[2];
    O4[0] = fz; O4[1] = fz;

    __shared__ __align__(16) half_t sh[2][2048];
    __shared__ float lsh[2][32];

    half8 r0[4];
    float lr[4];
    const int srcoff = (t >> 7) * 2048 + hf * 1024 + ((t * 8) & 1023);

    auto LOADH = [&](int h) {
        const size_t base = ((((size_t)(b * 8 + h) * 64 + nt) << 12)) + srcoff;
#pragma unroll
        for (int q = 0; q < 4; ++q)
            r0[q] = *(const half8*)(oh + (size_t)q * 4194304 + base);
        if (t < 32) {
            const size_t li = (size_t)(b * 8 + h) * N_ + nt * 64 + hf * 32 + t;
#pragma unroll
            for (int q = 0; q < 4; ++q) lr[q] = lbuf[(size_t)q * 65536 + li];
        }
    };

    LOADH(0);
    for (int h = 0; h < 8; ++h) {
        const int buf = h & 1;
        const half8 s0 = (r0[0] + r0[1]) + (r0[2] + r0[3]);
        *(half8*)(&sh[buf][t * 8]) = s0;
        if (t < 32)
            lsh[buf][t] = __builtin_amdgcn_rcpf((lr[0] + lr[1]) + (lr[2] + lr[3]));
        __syncthreads();
        if (h < 7) LOADH(h + 1);          // prefetch next h under the MFMAs

        floatx4 acc[2];
        acc[0] = fz; acc[1] = fz;
#pragma unroll
        for (int c2 = 0; c2 < 2; ++c2) {
            const half8 af = *(const half8*)(Ab + (h * 8 + c2 * 4 + g) * 128 + c * 8);
#pragma unroll
            for (int ns = 0; ns < 2; ++ns) {
                const half8 bf = *(const half8*)(&sh[buf][(c2 * 2 + ns) * 512 + L * 8]);
                acc[ns] = __builtin_amdgcn_mfma_f32_16x16x32_f16(af, bf, acc[ns], 0, 0, 0);
            }
        }
#pragma unroll
        for (int ns = 0; ns < 2; ++ns) {
            const float inv = lsh[buf][ns * 16 + c];
#pragma unroll
            for (int i = 0; i < 4; ++i) O4[ns][i] = fmaf(acc[ns][i], inv, O4[ns][i]);
        }
    }

    float* Cg = out + ((size_t)b * DIM_ + mt * 16) * N_ + nt * 64 + hf * 32;
#pragma unroll
    for (int ns = 0; ns < 2; ++ns)
#pragma unroll
        for (int i = 0; i < 4; ++i)
            Cg[(size_t)(4 * g + i) * N_ + ns * 16 + c] = O4[ns][i];
}

extern "C" void kernel_launch(void* const* d_in, const int* in_sizes, int n_in,
                              void* d_out, int out_size, void* d_ws, size_t ws_size,
                              hipStream_t stream) {
    const float* fmap  = (const float*)d_in[0];
    const float* w_qkv = (const float*)d_in[1];
    const float* w_out = (const float*)d_in[2];
    float* out = (float*)d_out;

    char* ws = (char*)d_ws;
    // Overlay plan: xTg and wqF are dead after mm_qkv; attn's oh overlays them.
    half_t* perm = (half_t*)ws;                       // 25,165,824 B
    float*  sq   = (float*) (ws + 25165824);          //    524,288 B
    float*  lbuf = (float*) (ws + 25690112);          // 4 x 262,144 B
    half_t* woF  = (half_t*)(ws + 26738688);          //    262,144 B (read by mm_out)
    half_t* oh   = (half_t*)(ws + 27000832);          // 4 x 8,388,608 B (after mm_qkv)
    half_t* xTg  = (half_t*)(ws + 27000832);          //  4,194,304 B (aliases oh)
    half_t* wqF  = (half_t*)(ws + 31195136);          //    786,432 B (aliases oh)

    prep_all <<<624, 256, 0, stream>>>(fmap, w_qkv, w_out, wqF, woF, xTg);
    mm_qkv_mf<<<dim3(64, 12, 2), 256, 0, stream>>>(wqF, xTg, perm, sq);
    attn_mfma<<<dim3(64, 8, 2), 512, 0, stream>>>(perm, sq, oh, lbuf);
    mm_out_mf<<<dim3(128, 4, 2), 256, 0, stream>>>(woF, oh, lbuf, out);
}

// Round 21
// 178.438 us; speedup vs baseline: 1.0580x; 1.0580x over previous
//
#include <hip/hip_runtime.h>

#define B_      2
#define DIM_    256
#define N_      4096
#define HEADS_  8
#define DINNER_ 512

typedef _Float16 half_t;
typedef _Float16 half8  __attribute__((ext_vector_type(8)));
typedef _Float16 half4v __attribute__((ext_vector_type(4)));
typedef _Float16 half2v __attribute__((ext_vector_type(2)));
typedef float    floatx4 __attribute__((ext_vector_type(4)));

#define SCL_    1.4426950408889634f  // log2(e), baked into Q,K
#define SHIFT2_ 20.0f                // fixed softmax shift (log2 domain)

// K=32 granule (64kappa x 64mu): halfoff(kappa,mu) =
//   ((kappa>>5)*4 + (mu>>4))*512 + (((kappa>>3)&3)*16 + (mu&15))*8 + (kappa&7)
// V tiles use a K=32 granule with the PV slot map chosen so the P B-frag is
// lane-local (co-designed with the QK output layout).
// perm: [b][slab 0..23][ntile 0..63][4096 halfs]; slab<8: Q, <16: K, else V.
//   Q slabs store -2*SCL*q; K slabs store SCL*k.
// xTg:  [b][ntile 0..63][kslab 0..3][4096 halfs]  (fmap in granule layout)
// Distance augmentation: S~ = (-2SCLq)·(SCLk) + q2*1 + 1*k2 = SCL^2*d2 via one
// extra K=32 MFMA whose operands carry [q2_hi,q2_lo,1,1] / [1,1,k2_hi,k2_lo].
// SCHEDULING NOTE (R2/R11/R17): attn pipe-busy is invariant under source-level
// scheduling (rotation+setprio, SW pipeline, SGB interleave all cost occupancy
// and added idle). v5 structure at 3 blocks/CU is the pipe-sum floor. Do not
// re-attempt schedule engineering here.

// ---------------- prep: weights -> A-frag fp16; fmap -> xTg granule fp16 -----
__global__ __launch_bounds__(256) void prep_all(const float* __restrict__ fmap,
                                                const float* __restrict__ w_qkv,
                                                const float* __restrict__ w_out,
                                                half_t* __restrict__ wqF,
                                                half_t* __restrict__ woF,
                                                half_t* __restrict__ xTg) {
    const int t = threadIdx.x, bx = blockIdx.x;
    __shared__ float Tl[64 * 68];
    if (bx < 96) {                 // w_qkv: 96 m-tiles x 256 k
        half_t* dst = wqF + (size_t)bx * 4096;
#pragma unroll
        for (int j = 0; j < 2; ++j) {
            const int cch = j * 256 + t;
            const int o = cch >> 4, m15 = cch & 15;
            const float4 a  = *(const float4*)&w_qkv[(size_t)(bx * 16 + m15) * 256 + o * 8];
            const float4 bb = *(const float4*)&w_qkv[(size_t)(bx * 16 + m15) * 256 + o * 8 + 4];
            half8 hv;
            hv[0] = (half_t)a.x;  hv[1] = (half_t)a.y;  hv[2] = (half_t)a.z;  hv[3] = (half_t)a.w;
            hv[4] = (half_t)bb.x; hv[5] = (half_t)bb.y; hv[6] = (half_t)bb.z; hv[7] = (half_t)bb.w;
            *(half8*)(dst + o * 128 + m15 * 8) = hv;
        }
    } else if (bx < 112) {         // w_out: 16 m-tiles x 512 k
        const int mt = bx - 96;
        half_t* dst = woF + (size_t)mt * 8192;
#pragma unroll
        for (int j = 0; j < 4; ++j) {
            const int cch = j * 256 + t;
            const int o = cch >> 4, m15 = cch & 15;
            const float4 a  = *(const float4*)&w_out[(size_t)(mt * 16 + m15) * 512 + o * 8];
            const float4 bb = *(const float4*)&w_out[(size_t)(mt * 16 + m15) * 512 + o * 8 + 4];
            half8 hv;
            hv[0] = (half_t)a.x;  hv[1] = (half_t)a.y;  hv[2] = (half_t)a.z;  hv[3] = (half_t)a.w;
            hv[4] = (half_t)bb.x; hv[5] = (half_t)bb.y; hv[6] = (half_t)bb.z; hv[7] = (half_t)bb.w;
            *(half8*)(dst + o * 128 + m15 * 8) = hv;
        }
    } else {                       // fmap [k][n] fp32 -> xTg granule fp16
        const int idx = bx - 112;
        const int n0 = (idx & 63) * 64, k0 = ((idx >> 6) & 3) * 64, b = idx >> 8;
        {
            const int kk = t >> 2, nq = (t & 3) * 16;
#pragma unroll
            for (int q = 0; q < 4; ++q) {
                float4 v = *(const float4*)&fmap[((size_t)b * DIM_ + k0 + kk) * N_ + n0 + nq + 4 * q];
                *(float4*)&Tl[kk * 68 + nq + 4 * q] = v;
            }
        }
        __syncthreads();
        {
            const int n = t >> 2, ko = (t & 3) * 16;   // kappa_local = ko..ko+15
            half8 h0, h1;
#pragma unroll
            for (int j = 0; j < 8; ++j) h0[j] = (half_t)Tl[(ko + j) * 68 + n];
#pragma unroll
            for (int j = 0; j < 8; ++j) h1[j] = (half_t)Tl[(ko + 8 + j) * 68 + n];
            half_t* dst = xTg + (((size_t)b * 64 + (n0 >> 6)) * 4 + (k0 >> 6)) * 4096;
            const int o0 = ((ko >> 5) * 4 + (n >> 4)) * 512 + (((ko >> 3) & 3) * 16 + (n & 15)) * 8;
            const int k8 = ko + 8;
            const int o1 = ((k8 >> 5) * 4 + (n >> 4)) * 512 + (((k8 >> 3) & 3) * 16 + (n & 15)) * 8;
            *(half8*)(dst + o0) = h0;
            *(half8*)(dst + o1) = h1;
        }
    }
}

// ---------------- GEMM1: qkv projection + fused sq; B staged in LDS ---------
// v4 (kept, R17: others 82.4 -> 74.7 us): by-pairing — each block computes TWO
// adjacent m-slabs per staged B-tile, halving xTg re-reads (grid y 24 -> 12).
__global__ __launch_bounds__(256) void mm_qkv_mf(const half_t* __restrict__ wqF,
                                                 const half_t* __restrict__ xTg,
                                                 half_t* __restrict__ perm,
                                                 float* __restrict__ sq) {
    const int nt64 = blockIdx.x, by2 = blockIdx.y, b = blockIdx.z;
    const int t = threadIdx.x, w = t >> 6, L = t & 63, c = L & 15, g = L >> 4;

    const half_t* Ab0 = wqF + (size_t)(8 * by2 + w) * 4096;
    const half_t* Ab1 = Ab0 + 4 * 4096;
    const half_t* Bb  = xTg + (((size_t)b * 64 + nt64) * 4) * 4096;

    __shared__ __align__(16) char smraw[16384];
    half_t* Bsh = (half_t*)smraw;                 // 8192 halfs staged per phase
    half_t* VtH = (half_t*)smraw;                 // epilogue granule bounce (alias)
    float*  red = (float*)(smraw + 8192);         // sq reduction, stride 17

    const floatx4 fz = {0.f, 0.f, 0.f, 0.f};
    floatx4 acc0[4], acc1[4];
#pragma unroll
    for (int ns = 0; ns < 4; ++ns) { acc0[ns] = fz; acc1[ns] = fz; }

#pragma unroll
    for (int ph = 0; ph < 2; ++ph) {
        if (ph) __syncthreads();                   // waves done reading stage 0
#pragma unroll
        for (int j = 0; j < 4; ++j)
            *(half8*)&Bsh[(j * 256 + t) * 8] = *(const half8*)(Bb + ph * 8192 + (j * 256 + t) * 8);
        __syncthreads();
#pragma unroll
        for (int kk = 0; kk < 4; ++kk) {
            const int kc = ph * 4 + kk;
            const half8 af0 = *(const half8*)(Ab0 + (kc * 4 + g) * 128 + c * 8);
            const half8 af1 = *(const half8*)(Ab1 + (kc * 4 + g) * 128 + c * 8);
            const half_t* Bs = Bsh + (kk >> 1) * 4096 + (kk & 1) * 2048;
#pragma unroll
            for (int ns = 0; ns < 4; ++ns) {
                const half8 bf = *(const half8*)(Bs + ns * 512 + L * 8);
                acc0[ns] = __builtin_amdgcn_mfma_f32_16x16x32_f16(af0, bf, acc0[ns], 0, 0, 0);
                acc1[ns] = __builtin_amdgcn_mfma_f32_16x16x32_f16(af1, bf, acc1[ns], 0, 0, 0);
            }
        }
    }
    __syncthreads();                               // Bsh dead; VtH/red may write

#pragma unroll
    for (int e = 0; e < 2; ++e) {
        if (e) __syncthreads();                    // VtH/red reuse between halves
        const int by = by2 * 2 + e;
        half_t* dst = perm + (((size_t)(b * 24 + by) * 64 + nt64) << 12);
        if (by < 16) {
            // Q/K: f = SCL*val rounded to fp16; granule stores qs*f (qs=-2 for Q).
            const float qs = (by < 8) ? -2.0f : 1.0f;
            float part[4];
#pragma unroll
            for (int ns = 0; ns < 4; ++ns) {
                const floatx4 av4 = e ? acc1[ns] : acc0[ns];
                half_t m[4];
                float s = 0.f;
#pragma unroll
                for (int i = 0; i < 4; ++i) {
                    const half_t hq = (half_t)(av4[i] * SCL_);
                    const float f = (float)hq;
                    s = fmaf(f, f, s);
                    m[i] = (half_t)(qs * f);
                }
                part[ns] = s;
                const int off = ((w >> 1) * 4 + ns) * 512 + (((2 * w + (g >> 1)) & 3) * 16 + c) * 8 + 4 * (g & 1);
                half2v p0v, p1v;
                p0v[0] = m[0]; p0v[1] = m[1];
                p1v[0] = m[2]; p1v[1] = m[3];
                *(half2v*)(VtH + off)     = p0v;
                *(half2v*)(VtH + off + 2) = p1v;
            }
#pragma unroll
            for (int ns = 0; ns < 4; ++ns)
                red[(ns * 16 + (w * 4 + g)) * 17 + c] = part[ns];
            __syncthreads();
#pragma unroll
            for (int j = 0; j < 2; ++j)
                *(half8*)(dst + t * 16 + j * 8) = *(half8*)(VtH + t * 16 + j * 8);
            if (t < 64) {
                const int ns = t >> 4, cc = t & 15;
                float s = 0.f;
#pragma unroll
                for (int wg = 0; wg < 16; ++wg) s += red[(ns * 16 + wg) * 17 + cc];
                const int tens = by >> 3, hh = by & 7;
                sq[((size_t)(tens * 16 + b * 8 + hh)) * N_ + nt64 * 64 + ns * 16 + cc] = s;
            }
        } else {
            // V: j = 16ns+c (spatial key), dd = 16w+4g+i -> K=32 PV granule
#pragma unroll
            for (int ns = 0; ns < 4; ++ns) {
                const floatx4 av4 = e ? acc1[ns] : acc0[ns];
#pragma unroll
                for (int i = 0; i < 4; ++i)
                    VtH[((ns >> 1) * 4 + w) * 512 + ((c >> 2) * 16 + 4 * g + i) * 8 + (ns & 1) * 4 + (c & 3)] =
                        (half_t)av4[i];
            }
            __syncthreads();
#pragma unroll
            for (int j = 0; j < 2; ++j)
                *(half8*)(dst + t * 16 + j * 8) = *(half8*)(VtH + t * 16 + j * 8);
        }
    }
}

// ---------------- fused distance-attention, split-K x4, no-drain pipeline ----
// v5 (verified 98.5 us x2; REVERTED from v7 SGB per R17: VGPR 80, occ 21.8%,
// +16 us idle): 512 thr, dbuf K/V, reg prefetch, lgkm-only barrier, distance
// augmentation; softmax chain is sqrt->sub->exp2 only.
__global__ __launch_bounds__(512) void attn_mfma(const half_t* __restrict__ perm,
                                                 const float* __restrict__ sq,
                                                 half_t* __restrict__ oh,
                                                 float* __restrict__ lbuf) {
    const int bx = blockIdx.x;
    const int qb = bx & 15, kh = bx >> 4;
    const int h = blockIdx.y, b = blockIdx.z;
    const int bh = b * HEADS_ + h;

    const half_t* Qb = perm + ((size_t)(b * 24 + h) << 18);
    const half_t* Kb = perm + ((size_t)(b * 24 + 8 + h) << 18);
    const half_t* Vb = perm + ((size_t)(b * 24 + 16 + h) << 18);
    const float* q2a = sq + (size_t)bh * N_;
    const float* k2a = sq + (size_t)(16 + bh) * N_;

    __shared__ __align__(16) half_t Kl[2][4096];
    __shared__ __align__(16) half_t Vl[2][4096];
    __shared__ __align__(16) unsigned int k2lp[1024];   // packed {k2hi,k2lo}

    const int t = threadIdx.x, w = t >> 6, L = t & 63, c = L & 15, g = L >> 4;
    const floatx4 fz = {0.f, 0.f, 0.f, 0.f};

    // stage packed hi/lo k2 (4 KB) once; visible after iter-0 barrier
    {
        const float2 kv = *(const float2*)&k2a[kh * 1024 + t * 2];
        const half_t h0 = (half_t)kv.x; const half_t l0 = (half_t)(kv.x - (float)h0);
        const half_t h1 = (half_t)kv.y; const half_t l1 = (half_t)(kv.y - (float)h1);
        k2lp[t * 2]     = (unsigned)__builtin_bit_cast(unsigned short, h0) |
                          ((unsigned)__builtin_bit_cast(unsigned short, l0) << 16);
        k2lp[t * 2 + 1] = (unsigned)__builtin_bit_cast(unsigned short, h1) |
                          ((unsigned)__builtin_bit_cast(unsigned short, l1) << 16);
    }

    // persistent Q B-frags for 2 subtiles
    const int tl = w >> 1;
    const int p0 = (w & 1) * 2, p1 = p0 + 1;
    const half_t* Qt = Qb + ((size_t)(qb * 4 + tl) << 12);
    const half8 bq0a = *(const half8*)(Qt + (0 * 4 + p0) * 512 + L * 8);
    const half8 bq1a = *(const half8*)(Qt + (1 * 4 + p0) * 512 + L * 8);
    const half8 bq0b = *(const half8*)(Qt + (0 * 4 + p1) * 512 + L * 8);
    const half8 bq1b = *(const half8*)(Qt + (1 * 4 + p1) * 512 + L * 8);

    union U8 { half8 v; unsigned int u[4]; };
    // aug B-frags: lanes L<16 (kappa'0..7) = {q2hi,q2lo,1,1,0..}; others zero
    U8 qXa, qXb;
    {
        const float q2la = q2a[qb * 256 + 64 * tl + 16 * p0 + c];
        const float q2lb = q2a[qb * 256 + 64 * tl + 16 * p1 + c];
        const half_t ha = (half_t)q2la; const half_t la = (half_t)(q2la - (float)ha);
        const half_t hb = (half_t)q2lb; const half_t lb_ = (half_t)(q2lb - (float)hb);
        const unsigned pka = (unsigned)__builtin_bit_cast(unsigned short, ha) |
                             ((unsigned)__builtin_bit_cast(unsigned short, la) << 16);
        const unsigned pkb = (unsigned)__builtin_bit_cast(unsigned short, hb) |
                             ((unsigned)__builtin_bit_cast(unsigned short, lb_) << 16);
        const bool lo16 = (L < 16);
        qXa.u[0] = lo16 ? pka : 0u; qXa.u[1] = lo16 ? 0x3C003C00u : 0u;
        qXa.u[2] = 0u; qXa.u[3] = 0u;
        qXb.u[0] = lo16 ? pkb : 0u; qXb.u[1] = lo16 ? 0x3C003C00u : 0u;
        qXb.u[2] = 0u; qXb.u[3] = 0u;
    }

    half8 aone8;   // ones row m=0 for K=32 l-MFMA
    {
        const half_t ov = (c == 0) ? (half_t)1.0f : (half_t)0.0f;
        aone8[0] = ov; aone8[1] = ov; aone8[2] = ov; aone8[3] = ov;
        aone8[4] = ov; aone8[5] = ov; aone8[6] = ov; aone8[7] = ov;
    }

    floatx4 Oa[4], Ob[4];
    floatx4 laca = fz, lacb = fz;
#pragma unroll
    for (int dt = 0; dt < 4; ++dt) { Oa[dt] = fz; Ob[dt] = fz; }

    const int kt0 = kh * 16;
    half8 rk = *(const half8*)(Kb + ((size_t)kt0 << 12) + t * 8);
    half8 rv = *(const half8*)(Vb + ((size_t)kt0 << 12) + t * 8);

    union H8 { half8 v; half2v h2[4]; };

    for (int it = 0; it < 16; ++it) {
        const int buf = it & 1;
        *(half8*)(&Kl[buf][t * 8]) = rk;     // waits vmcnt for rk/rv data dep only
        *(half8*)(&Vl[buf][t * 8]) = rv;
        // LDS-only barrier: vmcnt (prefetch) stays outstanding across it.
        asm volatile("s_waitcnt lgkmcnt(0)\n\ts_barrier" ::: "memory");
        if (it < 15) {                        // prefetch overlaps compute below
            rk = *(const half8*)(Kb + ((size_t)(kt0 + it + 1) << 12) + t * 8);
            rv = *(const half8*)(Vb + ((size_t)(kt0 + it + 1) << 12) + t * 8);
        }

#pragma unroll
        for (int ntp = 0; ntp < 2; ++ntp) {
            H8 ua, ub;   // K=32 P B-frags, filled lane-locally across the pair
#pragma unroll
            for (int hh = 0; hh < 2; ++hh) {
                const int nt = ntp * 2 + hh;
                const half8 ak0 = *(const half8*)(&Kl[buf][(0 * 4 + nt) * 512 + L * 8]);
                const half8 ak1 = *(const half8*)(&Kl[buf][(1 * 4 + nt) * 512 + L * 8]);
                // aug A-frag: lanes<16 = {1,1,k2hi,k2lo,0..}; lanes>=16 hit
                // structural zeros in qX so no masking needed.
                U8 kX;
                kX.u[0] = 0x3C003C00u;
                kX.u[1] = k2lp[it * 64 + nt * 16 + c];
                kX.u[2] = 0u; kX.u[3] = 0u;
                floatx4 Sa = __builtin_amdgcn_mfma_f32_16x16x32_f16(ak0, bq0a, fz, 0, 0, 0);
                Sa = __builtin_amdgcn_mfma_f32_16x16x32_f16(ak1, bq1a, Sa, 0, 0, 0);
                Sa = __builtin_amdgcn_mfma_f32_16x16x32_f16(kX.v, qXa.v, Sa, 0, 0, 0);
                floatx4 Sb = __builtin_amdgcn_mfma_f32_16x16x32_f16(ak0, bq0b, fz, 0, 0, 0);
                Sb = __builtin_amdgcn_mfma_f32_16x16x32_f16(ak1, bq1b, Sb, 0, 0, 0);
                Sb = __builtin_amdgcn_mfma_f32_16x16x32_f16(kX.v, qXb.v, Sb, 0, 0, 0);

                float pa[4], pb[4];
#pragma unroll
                for (int i = 0; i < 4; ++i) {
                    // S~ = SCL^2*d2 directly; |.| is a free src modifier on sqrt
                    pa[i] = __builtin_amdgcn_exp2f(
                        __builtin_amdgcn_sqrtf(__builtin_fabsf(Sa[i])) - SHIFT2_);
                    pb[i] = __builtin_amdgcn_exp2f(
                        __builtin_amdgcn_sqrtf(__builtin_fabsf(Sb[i])) - SHIFT2_);
                }
                ua.h2[2 * hh]     = __builtin_bit_cast(half2v, __builtin_amdgcn_cvt_pkrtz(pa[0], pa[1]));
                ua.h2[2 * hh + 1] = __builtin_bit_cast(half2v, __builtin_amdgcn_cvt_pkrtz(pa[2], pa[3]));
                ub.h2[2 * hh]     = __builtin_bit_cast(half2v, __builtin_amdgcn_cvt_pkrtz(pb[0], pb[1]));
                ub.h2[2 * hh + 1] = __builtin_bit_cast(half2v, __builtin_amdgcn_cvt_pkrtz(pb[2], pb[3]));
            }

            laca = __builtin_amdgcn_mfma_f32_16x16x32_f16(aone8, ua.v, laca, 0, 0, 0);
            lacb = __builtin_amdgcn_mfma_f32_16x16x32_f16(aone8, ub.v, lacb, 0, 0, 0);
#pragma unroll
            for (int dt = 0; dt < 4; ++dt) {
                const half8 av = *(const half8*)(&Vl[buf][(ntp * 4 + dt) * 512 + L * 8]);
                Oa[dt] = __builtin_amdgcn_mfma_f32_16x16x32_f16(av, ua.v, Oa[dt], 0, 0, 0);
                Ob[dt] = __builtin_amdgcn_mfma_f32_16x16x32_f16(av, ub.v, Ob[dt], 0, 0, 0);
            }
        }
    }

    // write unnormalized O-quarters (fp16, K=32 granule: kappa=dd, mu=16*plane+c)
    const int ntile = qb * 4 + tl;
    half_t* dst = oh + (size_t)kh * 4194304 + (((size_t)bh * 64 + ntile) << 12);
#pragma unroll
    for (int dt = 0; dt < 4; ++dt) {
        const int obase = ((dt >> 1) * 4) * 512 + (((2 * dt + (g >> 1)) & 3) * 16 + c) * 8 + 4 * (g & 1);
        const half2v a0 = __builtin_bit_cast(half2v, __builtin_amdgcn_cvt_pkrtz(Oa[dt][0], Oa[dt][1]));
        const half2v a1 = __builtin_bit_cast(half2v, __builtin_amdgcn_cvt_pkrtz(Oa[dt][2], Oa[dt][3]));
        *(half2v*)(dst + obase + p0 * 512)     = a0;
        *(half2v*)(dst + obase + p0 * 512 + 2) = a1;
        const half2v b0 = __builtin_bit_cast(half2v, __builtin_amdgcn_cvt_pkrtz(Ob[dt][0], Ob[dt][1]));
        const half2v b1 = __builtin_bit_cast(half2v, __builtin_amdgcn_cvt_pkrtz(Ob[dt][2], Ob[dt][3]));
        *(half2v*)(dst + obase + p1 * 512)     = b0;
        *(half2v*)(dst + obase + p1 * 512 + 2) = b1;
    }
    // l: row m=0 of lac -> lanes 0..15, reg 0
    if (L < 16) {
        const size_t lb0 = (size_t)kh * 65536 + (size_t)bh * N_ + qb * 256 + 64 * tl;
        lbuf[lb0 + 16 * p0 + L] = laca[0];
        lbuf[lb0 + 16 * p1 + L] = lacb[0];
    }
}

// ---------------- GEMM3: out projection + split-K x4 combine inline ----------
// v3: column-split — each block handles a 32-col half-tile (grid 128x4x2).
__global__ __launch_bounds__(256) void mm_out_mf(const half_t* __restrict__ woF,
                                                 const half_t* __restrict__ oh,
                                                 const float* __restrict__ lbuf,
                                                 float* __restrict__ out) {
    const int bx = blockIdx.x;               // nt = bx>>1 (64-col tile), hf = bx&1
    const int nt = bx >> 1, hf = bx & 1;
    const int mb = blockIdx.y, b = blockIdx.z;
    const int t = threadIdx.x, w = t >> 6, L = t & 63, c = L & 15, g = L >> 4;
    const int mt = mb * 4 + w;

    const half_t* Ab = woF + (size_t)mt * 8192;
    const floatx4 fz = {0.f, 0.f, 0.f, 0.f};
    floatx4 O4[2];
    O4[0] = fz; O4[1] = fz;

    __shared__ __align__(16) half_t sh[2][2048];
    __shared__ float lsh[2][32];

    half8 r0[4];
    float lr[4];
    const int srcoff = (t >> 7) * 2048 + hf * 1024 + ((t * 8) & 1023);

    auto LOADH = [&](int h) {
        const size_t base = ((((size_t)(b * 8 + h) * 64 + nt) << 12)) + srcoff;
#pragma unroll
        for (int q = 0; q < 4; ++q)
            r0[q] = *(const half8*)(oh + (size_t)q * 4194304 + base);
        if (t < 32) {
            const size_t li = (size_t)(b * 8 + h) * N_ + nt * 64 + hf * 32 + t;
#pragma unroll
            for (int q = 0; q < 4; ++q) lr[q] = lbuf[(size_t)q * 65536 + li];
        }
    };

    LOADH(0);
    for (int h = 0; h < 8; ++h) {
        const int buf = h & 1;
        const half8 s0 = (r0[0] + r0[1]) + (r0[2] + r0[3]);
        *(half8*)(&sh[buf][t * 8]) = s0;
        if (t < 32)
            lsh[buf][t] = __builtin_amdgcn_rcpf((lr[0] + lr[1]) + (lr[2] + lr[3]));
        __syncthreads();
        if (h < 7) LOADH(h + 1);          // prefetch next h under the MFMAs

        floatx4 acc[2];
        acc[0] = fz; acc[1] = fz;
#pragma unroll
        for (int c2 = 0; c2 < 2; ++c2) {
            const half8 af = *(const half8*)(Ab + (h * 8 + c2 * 4 + g) * 128 + c * 8);
#pragma unroll
            for (int ns = 0; ns < 2; ++ns) {
                const half8 bf = *(const half8*)(&sh[buf][(c2 * 2 + ns) * 512 + L * 8]);
                acc[ns] = __builtin_amdgcn_mfma_f32_16x16x32_f16(af, bf, acc[ns], 0, 0, 0);
            }
        }
#pragma unroll
        for (int ns = 0; ns < 2; ++ns) {
            const float inv = lsh[buf][ns * 16 + c];
#pragma unroll
            for (int i = 0; i < 4; ++i) O4[ns][i] = fmaf(acc[ns][i], inv, O4[ns][i]);
        }
    }

    float* Cg = out + ((size_t)b * DIM_ + mt * 16) * N_ + nt * 64 + hf * 32;
#pragma unroll
    for (int ns = 0; ns < 2; ++ns)
#pragma unroll
        for (int i = 0; i < 4; ++i)
            Cg[(size_t)(4 * g + i) * N_ + ns * 16 + c] = O4[ns][i];
}

extern "C" void kernel_launch(void* const* d_in, const int* in_sizes, int n_in,
                              void* d_out, int out_size, void* d_ws, size_t ws_size,
                              hipStream_t stream) {
    const float* fmap  = (const float*)d_in[0];
    const float* w_qkv = (const float*)d_in[1];
    const float* w_out = (const float*)d_in[2];
    float* out = (float*)d_out;

    char* ws = (char*)d_ws;
    // Overlay plan: xTg and wqF are dead after mm_qkv; attn's oh overlays them.
    half_t* perm = (half_t*)ws;                       // 25,165,824 B
    float*  sq   = (float*) (ws + 25165824);          //    524,288 B
    float*  lbuf = (float*) (ws + 25690112);          // 4 x 262,144 B
    half_t* woF  = (half_t*)(ws + 26738688);          //    262,144 B (read by mm_out)
    half_t* oh   = (half_t*)(ws + 27000832);          // 4 x 8,388,608 B (after mm_qkv)
    half_t* xTg  = (half_t*)(ws + 27000832);          //  4,194,304 B (aliases oh)
    half_t* wqF  = (half_t*)(ws + 31195136);          //    786,432 B (aliases oh)

    prep_all <<<624, 256, 0, stream>>>(fmap, w_qkv, w_out, wqF, woF, xTg);
    mm_qkv_mf<<<dim3(64, 12, 2), 256, 0, stream>>>(wqF, xTg, perm, sq);
    attn_mfma<<<dim3(64, 8, 2), 512, 0, stream>>>(perm, sq, oh, lbuf);
    mm_out_mf<<<dim3(128, 4, 2), 256, 0, stream>>>(woF, oh, lbuf, out);
}